// Round 4
// baseline (6555.085 us; speedup 1.0000x reference)
//
#include <hip/hip_runtime.h>
#include <hip/hip_bf16.h>
#include <cstdint>

// ============================================================================
// OverlapGATv2 forward, f32, workspace-tight (147.5 MB arena). OUTPUT = f32.
// Tower insight: only H-row 0 survives the stride chain; stages 1-5 need
// conv1 rows 0..22, conv2 0..10, conv3 0..4, conv4 0..1, conv5 row 0.
// Stages 6..12 are pure channel GEMMs. GAT/NetVLAD run in 8-sample chunks.
// ============================================================================

// ---------------- fused conv stages 1-5 (live rows only) --------------------
__global__ __launch_bounds__(256) void tower_k(
    const float* __restrict__ in,
    const float* __restrict__ w1, const float* __restrict__ w2,
    const float* __restrict__ w3, const float* __restrict__ w4,
    const float* __restrict__ w5, float* __restrict__ outA)
{
  __shared__ float wl[6144];        // staged weights (stages 1-3)
  __shared__ float bufA[8][370];
  __shared__ float bufB[8][370];
  const int col = threadIdx.x & 7;
  const int role = threadIdx.x >> 3;          // 0..31
  const int colg = blockIdx.x * 8 + col;
  const int b = colg / 900, w = colg - b * 900;
  for (int idx = role; idx < 135; idx += 32) {
    int ci = idx / 27, h = idx - ci * 27;
    bufA[col][idx] = in[((size_t)(b * 5 + ci) * 64 + h) * 900 + w];
  }
  for (int i = threadIdx.x; i < 400; i += 256) wl[i] = w1[i];
  __syncthreads();
  // stage1: Ci=5,kh=5,s=1, rows 0..22 -> bufB[co*23+ho], Co=16
  for (int o = role; o < 368; o += 32) {
    int co = o / 23, ho = o - co * 23;
    float acc = 0.f;
    for (int ci = 0; ci < 5; ++ci)
#pragma unroll
      for (int k = 0; k < 5; ++k)
        acc = fmaf(bufA[col][ci * 27 + ho + k], wl[(co * 5 + ci) * 5 + k], acc);
    bufB[col][o] = fmaxf(acc, 0.f);
  }
  __syncthreads();
  for (int i = threadIdx.x; i < 1536; i += 256) wl[i] = w2[i];
  __syncthreads();
  // stage2: Ci=16,kh=3,s=2, rows 0..10 -> bufA[co*11+ho], Co=32
  for (int o = role; o < 352; o += 32) {
    int co = o / 11, ho = o - co * 11;
    float acc = 0.f;
    for (int ci = 0; ci < 16; ++ci)
#pragma unroll
      for (int k = 0; k < 3; ++k)
        acc = fmaf(bufB[col][ci * 23 + 2 * ho + k], wl[(co * 16 + ci) * 3 + k], acc);
    bufA[col][o] = fmaxf(acc, 0.f);
  }
  __syncthreads();
  for (int i = threadIdx.x; i < 6144; i += 256) wl[i] = w3[i];
  __syncthreads();
  // stage3: Ci=32,kh=3,s=2, rows 0..4 -> bufB[co*5+ho], Co=64
  for (int o = role; o < 320; o += 32) {
    int co = o / 5, ho = o - co * 5;
    float acc = 0.f;
    for (int ci = 0; ci < 32; ++ci)
#pragma unroll
      for (int k = 0; k < 3; ++k)
        acc = fmaf(bufA[col][ci * 11 + 2 * ho + k], wl[(co * 32 + ci) * 3 + k], acc);
    bufB[col][o] = fmaxf(acc, 0.f);
  }
  __syncthreads();
  // stage4: Ci=64,kh=3,s=2, rows 0..1 -> bufA[co*2+ho], Co=64
  for (int o = role; o < 128; o += 32) {
    int co = o >> 1, ho = o & 1;
    float acc = 0.f;
    for (int ci = 0; ci < 64; ++ci) {
      const float* wp = &w4[(co * 64 + ci) * 3];
#pragma unroll
      for (int k = 0; k < 3; ++k)
        acc = fmaf(bufB[col][ci * 5 + 2 * ho + k], wp[k], acc);
    }
    bufA[col][o] = fmaxf(acc, 0.f);
  }
  __syncthreads();
  // stage5: Ci=64,kh=2,s=2, row 0 -> bufB[co], Co=128
  for (int o = role; o < 128; o += 32) {
    float acc = 0.f;
    for (int ci = 0; ci < 64; ++ci) {
      const float* wp = &w5[(o * 64 + ci) * 2];
      acc = fmaf(bufA[col][ci * 2 + 0], wp[0], acc);
      acc = fmaf(bufA[col][ci * 2 + 1], wp[1], acc);
    }
    bufB[col][o] = fmaxf(acc, 0.f);
  }
  __syncthreads();
  for (int c = role; c < 128; c += 32)
    outA[(size_t)colg * 128 + c] = bufB[col][c];
}

// ---------------- f32 GEMM 128x128, 8x8 micro, BK=16, M-guarded -------------
template <int TRANSB>
__global__ __launch_bounds__(256) void gemm128g_k(
    const float* __restrict__ A, const float* __restrict__ Bw,
    const float* __restrict__ bias, float* __restrict__ C,
    int Mc, int N, int K, int relu)
{
  __shared__ float As[16][132];
  __shared__ float Bs[16][132];
  const int tid = threadIdx.x;
  const int tx = tid % 16, ty = tid / 16;
  const int m0 = blockIdx.y * 128, n0 = blockIdx.x * 128;
  const int arow = tid >> 2, akq = (tid & 3) * 4;
  float acc[8][8] = {};
  for (int k0 = 0; k0 < K; k0 += 16) {
#pragma unroll
    for (int p = 0; p < 2; ++p) {
      int r = arow + p * 64;
      float4 v = make_float4(0.f, 0.f, 0.f, 0.f);
      if (m0 + r < Mc)
        v = *reinterpret_cast<const float4*>(&A[(size_t)(m0 + r) * K + k0 + akq]);
      As[akq + 0][r] = v.x; As[akq + 1][r] = v.y;
      As[akq + 2][r] = v.z; As[akq + 3][r] = v.w;
    }
    if (TRANSB) {
#pragma unroll
      for (int p = 0; p < 2; ++p) {
        int n = arow + p * 64;
        const float4 v = *reinterpret_cast<const float4*>(
            &Bw[(size_t)(n0 + n) * K + k0 + akq]);
        Bs[akq + 0][n] = v.x; Bs[akq + 1][n] = v.y;
        Bs[akq + 2][n] = v.z; Bs[akq + 3][n] = v.w;
      }
    } else {
      int kk = tid >> 4, nq = (tid & 15) * 4;
#pragma unroll
      for (int p = 0; p < 2; ++p) {
        const float4 v = *reinterpret_cast<const float4*>(
            &Bw[(size_t)(k0 + kk) * N + n0 + p * 64 + nq]);
        *reinterpret_cast<float4*>(&Bs[kk][p * 64 + nq]) = v;
      }
    }
    __syncthreads();
#pragma unroll
    for (int kk = 0; kk < 16; ++kk) {
      float a[8], bb[8];
      *reinterpret_cast<float4*>(&a[0]) =
          *reinterpret_cast<const float4*>(&As[kk][ty * 8]);
      *reinterpret_cast<float4*>(&a[4]) =
          *reinterpret_cast<const float4*>(&As[kk][ty * 8 + 4]);
      *reinterpret_cast<float4*>(&bb[0]) =
          *reinterpret_cast<const float4*>(&Bs[kk][tx * 8]);
      *reinterpret_cast<float4*>(&bb[4]) =
          *reinterpret_cast<const float4*>(&Bs[kk][tx * 8 + 4]);
#pragma unroll
      for (int i = 0; i < 8; ++i)
#pragma unroll
        for (int j = 0; j < 8; ++j)
          acc[i][j] = fmaf(a[i], bb[j], acc[i][j]);
    }
    __syncthreads();
  }
#pragma unroll
  for (int i = 0; i < 8; ++i) {
    int m = m0 + ty * 8 + i;
    if (m >= Mc) continue;
#pragma unroll
    for (int j = 0; j < 8; ++j) {
      int n = n0 + tx * 8 + j;
      float v = acc[i][j] + (bias ? bias[n] : 0.f);
      if (relu) v = fmaxf(v, 0.f);
      C[(size_t)m * N + n] = v;
    }
  }
}

// ---------------- f32 GEMM 64x64 tile (N=64), M-guarded ---------------------
__global__ __launch_bounds__(256) void gemm64g_k(
    const float* __restrict__ A, const float* __restrict__ Bw,
    const float* __restrict__ bias, float* __restrict__ C,
    int Mc, int N, int K)
{
  __shared__ float As[16][68];
  __shared__ float Bs[16][68];
  const int tid = threadIdx.x;
  const int tx = tid % 16, ty = tid / 16;
  const int m0 = blockIdx.y * 64, n0 = blockIdx.x * 64;
  const int arow = tid >> 2, akq = (tid & 3) * 4;
  float acc[4][4] = {};
  for (int k0 = 0; k0 < K; k0 += 16) {
    {
      float4 v = make_float4(0.f, 0.f, 0.f, 0.f);
      if (m0 + arow < Mc)
        v = *reinterpret_cast<const float4*>(&A[(size_t)(m0 + arow) * K + k0 + akq]);
      As[akq + 0][arow] = v.x; As[akq + 1][arow] = v.y;
      As[akq + 2][arow] = v.z; As[akq + 3][arow] = v.w;
    }
    {
      int kk = tid >> 4, nq = (tid & 15) * 4;
      const float4 v = *reinterpret_cast<const float4*>(
          &Bw[(size_t)(k0 + kk) * N + n0 + nq]);
      *reinterpret_cast<float4*>(&Bs[kk][nq]) = v;
    }
    __syncthreads();
#pragma unroll
    for (int kk = 0; kk < 16; ++kk) {
      float a[4], bb[4];
      *reinterpret_cast<float4*>(a) =
          *reinterpret_cast<const float4*>(&As[kk][ty * 4]);
      *reinterpret_cast<float4*>(bb) =
          *reinterpret_cast<const float4*>(&Bs[kk][tx * 4]);
#pragma unroll
      for (int i = 0; i < 4; ++i)
#pragma unroll
        for (int j = 0; j < 4; ++j)
          acc[i][j] = fmaf(a[i], bb[j], acc[i][j]);
    }
    __syncthreads();
  }
#pragma unroll
  for (int i = 0; i < 4; ++i) {
    int m = m0 + ty * 4 + i;
    if (m >= Mc) continue;
#pragma unroll
    for (int j = 0; j < 4; ++j) {
      int n = n0 + tx * 4 + j;
      C[(size_t)m * N + n] = acc[i][j] + bias[n];
    }
  }
}

// ---------------- GATv2 attention, chunk-local (8 samples = 7200 waves) -----
template <int FO>
__global__ __launch_bounds__(256) void gat_attn_k(
    const float* __restrict__ XL, const float* __restrict__ XR,
    const float* __restrict__ att, float* __restrict__ H /* in RES, out H */)
{
  const int wid = blockIdx.x * 4 + (threadIdx.x >> 6);   // 0..7199 local
  const int lane = threadIdx.x & 63;
  const int bl = wid / 900, d = wid - bl * 900;
  constexpr int C = FO / 64;
  const size_t base = (size_t)bl * 900 * FO;
  float xr[C], at[C];
#pragma unroll
  for (int c = 0; c < C; ++c) {
    xr[c] = XR[base + (size_t)d * FO + c * 64 + lane];
    at[c] = att[c * 64 + lane];
  }
  float e[30];
#pragma unroll
  for (int j = 0; j < 30; ++j) {
    int s = d + j - 14; if (s < 0) s += 900; if (s >= 900) s -= 900;
    float p = 0.f;
#pragma unroll
    for (int c = 0; c < C; ++c) {
      float v = XL[base + (size_t)s * FO + c * 64 + lane] + xr[c];
      v = v > 0.f ? v : 0.2f * v;       // leaky_relu 0.2
      p = fmaf(v, at[c], p);
    }
#pragma unroll
    for (int off = 32; off >= 1; off >>= 1) p += __shfl_xor(p, off, 64);
    e[j] = p;
  }
  float m = e[0];
#pragma unroll
  for (int j = 1; j < 30; ++j) m = fmaxf(m, e[j]);
  float sum = 0.f;
#pragma unroll
  for (int j = 0; j < 30; ++j) { e[j] = __expf(e[j] - m); sum += e[j]; }
  float inv = 1.f / sum;
  float acc[C] = {};
#pragma unroll
  for (int j = 0; j < 30; ++j) {
    int s = d + j - 14; if (s < 0) s += 900; if (s >= 900) s -= 900;
    float al = e[j] * inv;
#pragma unroll
    for (int c = 0; c < C; ++c)
      acc[c] = fmaf(al, XL[base + (size_t)s * FO + c * 64 + lane], acc[c]);
  }
#pragma unroll
  for (int c = 0; c < C; ++c) {
    size_t idx = base + (size_t)d * FO + c * 64 + lane;
    H[idx] = acc[c] + H[idx];
  }
}

// ---------------- L2-normalize rows of 1024 (in place) ----------------------
__global__ __launch_bounds__(256) void norm1024_k(float* __restrict__ x)
{
  float* p = x + (size_t)blockIdx.x * 1024;
  int t = threadIdx.x;
  float4 v = reinterpret_cast<float4*>(p)[t];
  float ss = v.x * v.x + v.y * v.y + v.z * v.z + v.w * v.w;
#pragma unroll
  for (int off = 32; off >= 1; off >>= 1) ss += __shfl_xor(ss, off, 64);
  __shared__ float w4[4];
  if ((t & 63) == 0) w4[t >> 6] = ss;
  __syncthreads();
  float tot = w4[0] + w4[1] + w4[2] + w4[3];
  float sc = 1.f / fmaxf(sqrtf(tot), 1e-12f);
  v.x *= sc; v.y *= sc; v.z *= sc; v.w *= sc;
  reinterpret_cast<float4*>(p)[t] = v;
}

// ---------------- softmax rows of 64 (wave/row) -----------------------------
__global__ __launch_bounds__(256) void softmax64_k(float* __restrict__ x)
{
  int r = blockIdx.x * 4 + (threadIdx.x >> 6);
  int lane = threadIdx.x & 63;
  float v = x[(size_t)r * 64 + lane];
  float m = v;
#pragma unroll
  for (int off = 32; off >= 1; off >>= 1) m = fmaxf(m, __shfl_xor(m, off, 64));
  v = __expf(v - m);
  float s = v;
#pragma unroll
  for (int off = 32; off >= 1; off >>= 1) s += __shfl_xor(s, off, 64);
  x[(size_t)r * 64 + lane] = v / s;
}

// ---------------- asum[s,k] = sum_n actc[s,n,k] (chunk-local) ---------------
__global__ __launch_bounds__(256) void colsum_chunk_k(
    const float* __restrict__ actc, float* __restrict__ asumBase)
{
  int s = blockIdx.x;
  int lane = threadIdx.x & 63, wv = threadIdx.x >> 6;
  const float* ab = actc + (size_t)s * 900 * 64;
  float sum = 0.f;
  for (int n = wv; n < 900; n += 4) sum += ab[(size_t)n * 64 + lane];
  __shared__ float tmp[4][64];
  tmp[wv][lane] = sum;
  __syncthreads();
  if (wv == 0)
    asumBase[s * 64 + lane] = tmp[0][lane] + tmp[1][lane] + tmp[2][lane] + tmp[3][lane];
}

// ---------------- vlad[s,f,k] = sum_n act*feats - asum*cw2 (chunk) ----------
__global__ __launch_bounds__(256) void vlad_chunk_k(
    const float* __restrict__ featsc, const float* __restrict__ actc,
    const float* __restrict__ asumBase, const float* __restrict__ cw2,
    float* __restrict__ vladBase)
{
  int s = blockIdx.y, f0 = blockIdx.x * 64;
  int tx = threadIdx.x % 16, ty = threadIdx.x / 16;
  __shared__ float Fs[16][68];
  __shared__ float Ks[16][68];
  float acc[4][4] = {};
  const float* fb = featsc + (size_t)s * 900 * 1024;
  const float* ab = actc + (size_t)s * 900 * 64;
  int nr = threadIdx.x / 16, cq = (threadIdx.x % 16) * 4;
  for (int n0 = 0; n0 < 900; n0 += 16) {
    int n = n0 + nr;
    float4 fv = make_float4(0.f, 0.f, 0.f, 0.f);
    float4 av = make_float4(0.f, 0.f, 0.f, 0.f);
    if (n < 900) {
      fv = *reinterpret_cast<const float4*>(&fb[(size_t)n * 1024 + f0 + cq]);
      av = *reinterpret_cast<const float4*>(&ab[(size_t)n * 64 + cq]);
    }
    *reinterpret_cast<float4*>(&Fs[nr][cq]) = fv;
    *reinterpret_cast<float4*>(&Ks[nr][cq]) = av;
    __syncthreads();
#pragma unroll
    for (int kk = 0; kk < 16; ++kk) {
      float a[4], c[4];
      *reinterpret_cast<float4*>(a) =
          *reinterpret_cast<const float4*>(&Fs[kk][ty * 4]);
      *reinterpret_cast<float4*>(c) =
          *reinterpret_cast<const float4*>(&Ks[kk][tx * 4]);
#pragma unroll
      for (int i = 0; i < 4; ++i)
#pragma unroll
        for (int j = 0; j < 4; ++j)
          acc[i][j] = fmaf(a[i], c[j], acc[i][j]);
    }
    __syncthreads();
  }
#pragma unroll
  for (int i = 0; i < 4; ++i) {
    int f = f0 + ty * 4 + i;
#pragma unroll
    for (int j = 0; j < 4; ++j) {
      int k = tx * 4 + j;
      vladBase[((size_t)s * 1024 + f) * 64 + k] =
          acc[i][j] - asumBase[s * 64 + k] * cw2[f * 64 + k];
    }
  }
}

// ---------------- intra-normalize vlad over f; emit global scale ------------
__global__ __launch_bounds__(256) void vlad_norm_k(
    float* __restrict__ vlad, float* __restrict__ gscale)
{
  int b = blockIdx.x;
  int lane = threadIdx.x & 63, wv = threadIdx.x >> 6;
  float* vb = vlad + (size_t)b * 1024 * 64;
  float ss = 0.f;
  for (int f = wv; f < 1024; f += 4) {
    float v = vb[(size_t)f * 64 + lane];
    ss = fmaf(v, v, ss);
  }
  __shared__ float tmp[4][64];
  tmp[wv][lane] = ss;
  __syncthreads();
  float tot = tmp[0][lane] + tmp[1][lane] + tmp[2][lane] + tmp[3][lane];
  float nrm = sqrtf(tot);
  float sc = 1.f / fmaxf(nrm, 1e-12f);
  if (wv == 0) {
    float c = nrm * sc;  // column-k contribution after intra-norm
    c = c * c;
#pragma unroll
    for (int off = 32; off >= 1; off >>= 1) c += __shfl_xor(c, off, 64);
    if (lane == 0) gscale[b] = 1.f / fmaxf(sqrtf(c), 1e-12f);
  }
  for (int f = wv; f < 1024; f += 4)
    vb[(size_t)f * 64 + lane] *= sc;
}

// ---------------- hidden = vlad[32,65536] @ hw[65536,256], split-K ----------
__global__ __launch_bounds__(256) void hidden_partial_k(
    const float* __restrict__ vlad, const float* __restrict__ hw,
    float* __restrict__ partial)
{
  int o = threadIdx.x;
  int chunk = blockIdx.x;
  int k0 = chunk * 512;
  float acc[32] = {};
  for (int k = k0; k < k0 + 512; ++k) {
    float h = hw[(size_t)k * 256 + o];
#pragma unroll
    for (int b = 0; b < 32; ++b)
      acc[b] = fmaf(vlad[(size_t)b * 65536 + k], h, acc[b]);
  }
#pragma unroll
  for (int b = 0; b < 32; ++b)
    partial[((size_t)chunk * 32 + b) * 256 + o] = acc[b];
}

__global__ __launch_bounds__(256) void hidden_reduce_k(
    const float* __restrict__ partial, const float* __restrict__ gscale,
    float* __restrict__ hidden)
{
  int b = blockIdx.x, o = threadIdx.x;
  float s = 0.f;
  for (int c = 0; c < 128; ++c) s += partial[((size_t)c * 32 + b) * 256 + o];
  hidden[b * 256 + o] = s * gscale[b];
}

// ---------------- BN + gating + final L2 norm -> f32 ------------------------
__global__ __launch_bounds__(256) void final_head_k(
    const float* __restrict__ hidden, const float* __restrict__ bn_g,
    const float* __restrict__ bn_b, const float* __restrict__ gw,
    const float* __restrict__ gb, float* __restrict__ out)
{
  int b = blockIdx.x, o = threadIdx.x;
  __shared__ float vs[256];
  const float inv_bn = 0.99999500003749968f;  // 1/sqrt(1+1e-5)
  float v = hidden[b * 256 + o] * inv_bn * bn_g[o] + bn_b[o];
  vs[o] = v;
  __syncthreads();
  float g = 0.f;
  for (int i = 0; i < 256; ++i) g = fmaf(vs[i], gw[i * 256 + o], g);
  g += gb[o];
  float sig = 1.f / (1.f + __expf(-g));
  float u = v * sig;
  float ss = u * u;
#pragma unroll
  for (int off = 32; off >= 1; off >>= 1) ss += __shfl_xor(ss, off, 64);
  __shared__ float t4[4];
  if ((o & 63) == 0) t4[o >> 6] = ss;
  __syncthreads();
  float tot = t4[0] + t4[1] + t4[2] + t4[3];
  float sc = 1.f / fmaxf(sqrtf(tot), 1e-12f);
  out[b * 256 + o] = u * sc;
}

// ---------------- ws-too-small diagnostic: emit zeros (f32) -----------------
__global__ __launch_bounds__(256) void zero_out_k(float* out, int n)
{
  int i = blockIdx.x * 256 + threadIdx.x;
  if (i < n) out[i] = 0.f;
}

// ============================================================================
extern "C" void kernel_launch(void* const* d_in, const int* in_sizes, int n_in,
                              void* d_out, int out_size, void* d_ws, size_t ws_size,
                              hipStream_t stream) {
  const float* x_l = (const float*)d_in[0];
  const float* wc[11];
  for (int i = 0; i < 11; ++i) wc[i] = (const float*)d_in[1 + i];
  const float* w_last1 = (const float*)d_in[12];
  const float* w_last2 = (const float*)d_in[13];
  const float* g_wl[3]   = {(const float*)d_in[14], (const float*)d_in[21], (const float*)d_in[28]};
  const float* g_bl[3]   = {(const float*)d_in[15], (const float*)d_in[22], (const float*)d_in[29]};
  const float* g_wr[3]   = {(const float*)d_in[16], (const float*)d_in[23], (const float*)d_in[30]};
  const float* g_br[3]   = {(const float*)d_in[17], (const float*)d_in[24], (const float*)d_in[31]};
  const float* g_att[3]  = {(const float*)d_in[18], (const float*)d_in[25], (const float*)d_in[32]};
  const float* g_res[3]  = {(const float*)d_in[19], (const float*)d_in[26], (const float*)d_in[33]};
  const float* g_bias[3] = {(const float*)d_in[20], (const float*)d_in[27], (const float*)d_in[34]};
  const float* nv_cw   = (const float*)d_in[35];
  const float* nv_cb   = (const float*)d_in[36];
  const float* nv_cw2  = (const float*)d_in[37];
  const float* nv_hw   = (const float*)d_in[38];
  const float* nv_bn_g = (const float*)d_in[39];
  const float* nv_bn_b = (const float*)d_in[40];
  const float* nv_gw   = (const float*)d_in[41];
  const float* nv_gb   = (const float*)d_in[42];
  float* out = (float*)d_out;   // reference output dtype is float32

  // ---- arena: 36,864,000 floats = 147.456 MB ----
  constexpr size_t S1 = 7372800;     // = 28800*256
  constexpr size_t S2 = 14745600;    // = 28800*512
  constexpr size_t S3 = 29491200;    // = S2 + 28800*512
  constexpr size_t ARENA = 36864000; // = S3 + 28800*256
  if (ws_size < ARENA * sizeof(float)) {
    zero_out_k<<<dim3((out_size + 255) / 256), dim3(256), 0, stream>>>(out, out_size);
    return;
  }
  float* W = (float*)d_ws;
  dim3 blk(256);

  // ---- phase 1: tower (stages 1-5 fused) + channel-GEMM chain (6..12) ----
  float* A5 = W + S1;                 // [28800,128]
  float* t0 = W + S1 + 3686400;       // [28800,128]
  float* t1 = W + S3;                 // [28800,128]
  float* nodes = W;                   // [28800,256]
  tower_k<<<dim3(3600), blk, 0, stream>>>(x_l, wc[0], wc[1], wc[2], wc[3], wc[4], A5);
  gemm128g_k<1><<<dim3(1, 225), blk, 0, stream>>>(A5, wc[5], nullptr, t0, 28800, 128, 128, 1);
  gemm128g_k<1><<<dim3(1, 225), blk, 0, stream>>>(t0, wc[6], nullptr, t1, 28800, 128, 128, 1);
  gemm128g_k<1><<<dim3(1, 225), blk, 0, stream>>>(t1, wc[7], nullptr, t0, 28800, 128, 128, 1);
  gemm128g_k<1><<<dim3(1, 225), blk, 0, stream>>>(t0, wc[8], nullptr, t1, 28800, 128, 128, 1);
  gemm128g_k<1><<<dim3(1, 225), blk, 0, stream>>>(t1, wc[9], nullptr, t0, 28800, 128, 128, 1);
  gemm128g_k<1><<<dim3(1, 225), blk, 0, stream>>>(t0, wc[10], nullptr, t1, 28800, 128, 128, 1);
  gemm128g_k<1><<<dim3(2, 225), blk, 0, stream>>>(t1, w_last1, nullptr, nodes, 28800, 256, 128, 1);

  float* H1 = W + S1;                 // [28800,256]
  float* H2 = W + S2;                 // [28800,512]
  float* H3 = W;                      // [28800,512]

  // ---- phase 2: GAT layer 1 (Fi=256, Fo=256), 4 chunks of 8 samples ----
  for (int c = 0; c < 4; ++c) {
    size_t Mb = (size_t)c * 7200;
    float* XLc = W + S2;              // [7200,256]
    float* XRc = W + S2 + 1843200;
    gemm128g_k<0><<<dim3(2, 57), blk, 0, stream>>>(nodes + Mb * 256, g_wl[0], g_bl[0], XLc, 7200, 256, 256, 0);
    gemm128g_k<0><<<dim3(2, 57), blk, 0, stream>>>(nodes + Mb * 256, g_wr[0], g_br[0], XRc, 7200, 256, 256, 0);
    gemm128g_k<0><<<dim3(2, 57), blk, 0, stream>>>(nodes + Mb * 256, g_res[0], g_bias[0], H1 + Mb * 256, 7200, 256, 256, 0);
    gat_attn_k<256><<<dim3(1800), blk, 0, stream>>>(XLc, XRc, g_att[0], H1 + Mb * 256);
  }
  // ---- phase 3: GAT layer 2 (256 -> 512) ----
  for (int c = 0; c < 4; ++c) {
    size_t Mb = (size_t)c * 7200;
    float* XLc = W;                   // [7200,512] (nodes dead)
    float* XRc = W + 3686400;
    gemm128g_k<0><<<dim3(4, 57), blk, 0, stream>>>(H1 + Mb * 256, g_wl[1], g_bl[1], XLc, 7200, 512, 256, 0);
    gemm128g_k<0><<<dim3(4, 57), blk, 0, stream>>>(H1 + Mb * 256, g_wr[1], g_br[1], XRc, 7200, 512, 256, 0);
    gemm128g_k<0><<<dim3(4, 57), blk, 0, stream>>>(H1 + Mb * 256, g_res[1], g_bias[1], H2 + Mb * 512, 7200, 512, 256, 0);
    gat_attn_k<512><<<dim3(1800), blk, 0, stream>>>(XLc, XRc, g_att[1], H2 + Mb * 512);
  }
  // ---- phase 4: GAT layer 3 (512 -> 512), H3 overwrites nodes+H1 ----
  for (int c = 0; c < 4; ++c) {
    size_t Mb = (size_t)c * 7200;
    float* XLc = W + S3;              // [7200,512]
    float* XRc = W + S3 + 3686400;
    gemm128g_k<0><<<dim3(4, 57), blk, 0, stream>>>(H2 + Mb * 512, g_wl[2], g_bl[2], XLc, 7200, 512, 512, 0);
    gemm128g_k<0><<<dim3(4, 57), blk, 0, stream>>>(H2 + Mb * 512, g_wr[2], g_br[2], XRc, 7200, 512, 512, 0);
    gemm128g_k<0><<<dim3(4, 57), blk, 0, stream>>>(H2 + Mb * 512, g_res[2], g_bias[2], H3 + Mb * 512, 7200, 512, 512, 0);
    gat_attn_k<512><<<dim3(1800), blk, 0, stream>>>(XLc, XRc, g_att[2], H3 + Mb * 512);
  }

  // ---- phase 5: feats -> act -> vlad, chunked (H2 region free) ----
  float* vlad = W + S3;               // [32,1024,64]
  float* asum = W + S3 + 2097152;     // [32,64]
  float* gsc  = W + S3 + 2099200;     // [32]
  float* hid  = W + S3 + 2099232;     // [32,256]
  float* part = W + S3 + 2200000;     // [128,32,256]
  for (int c = 0; c < 4; ++c) {
    size_t Mb = (size_t)c * 7200;
    int b0 = c * 8;
    float* fc = W + S2;               // [7200,1024]
    float* ac = W + S2 + 7372800;     // [7200,64]
    gemm128g_k<1><<<dim3(8, 57), blk, 0, stream>>>(H3 + Mb * 512, w_last2, nullptr, fc, 7200, 1024, 512, 1);
    norm1024_k<<<dim3(7200), blk, 0, stream>>>(fc);
    gemm64g_k<<<dim3(1, 113), blk, 0, stream>>>(fc, nv_cw, nv_cb, ac, 7200, 64, 1024);
    softmax64_k<<<dim3(1800), blk, 0, stream>>>(ac);
    colsum_chunk_k<<<dim3(8), blk, 0, stream>>>(ac, asum + b0 * 64);
    vlad_chunk_k<<<dim3(16, 8), blk, 0, stream>>>(fc, ac, asum + b0 * 64, nv_cw2, vlad + (size_t)b0 * 65536);
  }
  // ---- phase 6: normalize + hidden + head ----
  vlad_norm_k<<<dim3(32), blk, 0, stream>>>(vlad, gsc);
  hidden_partial_k<<<dim3(128), blk, 0, stream>>>(vlad, nv_hw, part);
  hidden_reduce_k<<<dim3(32), blk, 0, stream>>>(part, gsc, hid);
  final_head_k<<<dim3(32), blk, 0, stream>>>(hid, nv_bn_g, nv_bn_b, nv_gw, nv_gb, out);
  (void)in_sizes; (void)n_in; (void)ws_size;
}

// Round 5
// 3151.267 us; speedup vs baseline: 2.0801x; 2.0801x over previous
//
#include <hip/hip_runtime.h>
#include <hip/hip_bf16.h>
#include <cstdint>

// ============================================================================
// OverlapGATv2 forward. bf16-MFMA GEMMs + f32 attention/softmax/VLAD.
// Verified f32 anchor: round-4 (6555us, absmax 2.4e-4). This round:
//  - all big GEMMs -> mfma_f32_16x16x32_bf16 (A[M,K]bf16 @ Bt[N,K]bf16)
//  - hidden GEMM -> 1024-way split-K (was 39 GB/s, 1176us)
//  - attention reads bf16 XL/XR, writes bf16 H; math in f32
// Arena (byte offsets, peak 147,456,000 B = proven available):
//  P1 conv: CB0@0, CB1@8M, NODES@16M
//  P2 gat1: XL1@31M XR1@46M (bf16), RES1@61M (f32), H1B@0 (bf16)
//  P3 gat2 (4x8-sample chunks): XL2@15M XR2@23M bf16, RES2@31M f32, H2B@46M
//  P4 gat3: XL3@15M XR3@23M RES3@31M, H3B@76M
//  P5: FEAT@106M f32, FEATB@0 bf16, ACT@15M, VLAD@17M, ASUM/GSC/HID@25.5M
//  P6: PART@26M (33.5MB, over dead P3/P4 regions)
//  Weights bf16 @143M (4.19 MB)
// ============================================================================

typedef __bf16 bf16x8 __attribute__((ext_vector_type(8)));
typedef __bf16 bf16x4 __attribute__((ext_vector_type(4)));
typedef __bf16 bf16x2 __attribute__((ext_vector_type(2)));
typedef float f32x4 __attribute__((ext_vector_type(4)));

// ---------------- weight prep: cast & transpose-cast ------------------------
__global__ __launch_bounds__(256) void cast_bf16_k(
    const float* __restrict__ s, __bf16* __restrict__ d, int n)
{
  int i = blockIdx.x * 256 + threadIdx.x;
  if (i < n) d[i] = (__bf16)s[i];
}

// s[K][N] -> d[N][K]
__global__ __launch_bounds__(256) void transpose_cast_k(
    const float* __restrict__ s, __bf16* __restrict__ d, int K, int N)
{
  int i = blockIdx.x * 256 + threadIdx.x;
  if (i >= K * N) return;
  int k = i / N, n = i - k * N;
  d[(size_t)n * K + k] = (__bf16)s[i];
}

// ---------------- fused conv stages 1-5 (live rows only), bf16 out ----------
__global__ __launch_bounds__(256) void tower_k(
    const float* __restrict__ in,
    const float* __restrict__ w1, const float* __restrict__ w2,
    const float* __restrict__ w3, const float* __restrict__ w4,
    const float* __restrict__ w5, __bf16* __restrict__ outA)
{
  __shared__ float wl[6144];
  __shared__ float bufA[8][370];
  __shared__ float bufB[8][370];
  const int col = threadIdx.x & 7;
  const int role = threadIdx.x >> 3;
  const int colg = blockIdx.x * 8 + col;
  const int b = colg / 900, w = colg - b * 900;
  for (int idx = role; idx < 135; idx += 32) {
    int ci = idx / 27, h = idx - ci * 27;
    bufA[col][idx] = in[((size_t)(b * 5 + ci) * 64 + h) * 900 + w];
  }
  for (int i = threadIdx.x; i < 400; i += 256) wl[i] = w1[i];
  __syncthreads();
  for (int o = role; o < 368; o += 32) {            // s1: Ci=5 kh=5
    int co = o / 23, ho = o - co * 23;
    float acc = 0.f;
    for (int ci = 0; ci < 5; ++ci)
#pragma unroll
      for (int k = 0; k < 5; ++k)
        acc = fmaf(bufA[col][ci * 27 + ho + k], wl[(co * 5 + ci) * 5 + k], acc);
    bufB[col][o] = fmaxf(acc, 0.f);
  }
  __syncthreads();
  for (int i = threadIdx.x; i < 1536; i += 256) wl[i] = w2[i];
  __syncthreads();
  for (int o = role; o < 352; o += 32) {            // s2: Ci=16 kh=3 s2
    int co = o / 11, ho = o - co * 11;
    float acc = 0.f;
    for (int ci = 0; ci < 16; ++ci)
#pragma unroll
      for (int k = 0; k < 3; ++k)
        acc = fmaf(bufB[col][ci * 23 + 2 * ho + k], wl[(co * 16 + ci) * 3 + k], acc);
    bufA[col][o] = fmaxf(acc, 0.f);
  }
  __syncthreads();
  for (int i = threadIdx.x; i < 6144; i += 256) wl[i] = w3[i];
  __syncthreads();
  for (int o = role; o < 320; o += 32) {            // s3: Ci=32 kh=3 s2
    int co = o / 5, ho = o - co * 5;
    float acc = 0.f;
    for (int ci = 0; ci < 32; ++ci)
#pragma unroll
      for (int k = 0; k < 3; ++k)
        acc = fmaf(bufA[col][ci * 11 + 2 * ho + k], wl[(co * 32 + ci) * 3 + k], acc);
    bufB[col][o] = fmaxf(acc, 0.f);
  }
  __syncthreads();
  for (int o = role; o < 128; o += 32) {            // s4: Ci=64 kh=3 s2
    int co = o >> 1, ho = o & 1;
    float acc = 0.f;
    for (int ci = 0; ci < 64; ++ci) {
      const float* wp = &w4[(co * 64 + ci) * 3];
#pragma unroll
      for (int k = 0; k < 3; ++k)
        acc = fmaf(bufB[col][ci * 5 + 2 * ho + k], wp[k], acc);
    }
    bufA[col][o] = fmaxf(acc, 0.f);
  }
  __syncthreads();
  for (int o = role; o < 128; o += 32) {            // s5: Ci=64 kh=2 s2
    float acc = 0.f;
    for (int ci = 0; ci < 64; ++ci) {
      const float* wp = &w5[(o * 64 + ci) * 2];
      acc = fmaf(bufA[col][ci * 2 + 0], wp[0], acc);
      acc = fmaf(bufA[col][ci * 2 + 1], wp[1], acc);
    }
    bufB[col][o] = fmaxf(acc, 0.f);
  }
  __syncthreads();
  for (int c = role; c < 128; c += 32)
    outA[(size_t)colg * 128 + c] = (__bf16)bufB[col][c];
}

// ---------------- bf16 MFMA GEMM: C[M,N] = act(A[M,K] @ Bt[N,K]^T + bias) ---
// tile 128x128, BK=32, 4 waves in 2x2 (each 64x64 = 4x4 frags of 16x16x32).
// M,N arbitrary (guarded); K % 32 == 0. OUTBF16 selects output dtype.
template <int OUTBF16>
__global__ __launch_bounds__(256) void gemm_mfma_k(
    const __bf16* __restrict__ A, const __bf16* __restrict__ Bt,
    const float* __restrict__ bias, void* __restrict__ Cout,
    int M, int N, int K, int relu)
{
  constexpr int LDT = 40;   // bf16 row stride: 80B (16B-aligned frags, 2-way banks)
  __shared__ __bf16 As[128 * LDT];
  __shared__ __bf16 Bs[128 * LDT];
  const int tid = threadIdx.x;
  const int lane = tid & 63, wave = tid >> 6;
  const int wr = wave >> 1, wc = wave & 1;
  const int m0 = blockIdx.y * 128, n0 = blockIdx.x * 128;
  const int l16 = lane & 15, lk = lane >> 4;
  const int sr = tid >> 2;          // 0..63
  const int sc = (tid & 3) * 8;     // 0,8,16,24
  f32x4 acc[4][4] = {};
  for (int k0 = 0; k0 < K; k0 += 32) {
#pragma unroll
    for (int p = 0; p < 2; ++p) {
      int r = sr + p * 64;
      bf16x8 va = {};
      if (m0 + r < M)
        va = *(const bf16x8*)(A + (size_t)(m0 + r) * K + k0 + sc);
      *(bf16x8*)(As + r * LDT + sc) = va;
      bf16x8 vb = {};
      if (n0 + r < N)
        vb = *(const bf16x8*)(Bt + (size_t)(n0 + r) * K + k0 + sc);
      *(bf16x8*)(Bs + r * LDT + sc) = vb;
    }
    __syncthreads();
    bf16x8 af[4], bfr[4];
#pragma unroll
    for (int i = 0; i < 4; ++i) {
      af[i]  = *(const bf16x8*)(As + (wr * 64 + i * 16 + l16) * LDT + lk * 8);
      bfr[i] = *(const bf16x8*)(Bs + (wc * 64 + i * 16 + l16) * LDT + lk * 8);
    }
#pragma unroll
    for (int mi = 0; mi < 4; ++mi)
#pragma unroll
      for (int ni = 0; ni < 4; ++ni)
        acc[mi][ni] = __builtin_amdgcn_mfma_f32_16x16x32_bf16(
            af[mi], bfr[ni], acc[mi][ni], 0, 0, 0);
    __syncthreads();
  }
#pragma unroll
  for (int ni = 0; ni < 4; ++ni) {
    int colc = n0 + wc * 64 + ni * 16 + l16;
    if (colc >= N) continue;
    float bs = bias ? bias[colc] : 0.f;
#pragma unroll
    for (int mi = 0; mi < 4; ++mi) {
#pragma unroll
      for (int j = 0; j < 4; ++j) {
        int row = m0 + wr * 64 + mi * 16 + lk * 4 + j;
        if (row >= M) continue;
        float v = acc[mi][ni][j] + bs;
        if (relu) v = fmaxf(v, 0.f);
        if (OUTBF16)
          ((__bf16*)Cout)[(size_t)row * N + colc] = (__bf16)v;
        else
          ((float*)Cout)[(size_t)row * N + colc] = v;
      }
    }
  }
}

// ---------------- GATv2 attention: bf16 XL/XR in, f32 RES in, bf16 out ------
// dst d attends src d-14..d+15 (mod 900), 30 incl. self. One wave per dst.
template <int FO>
__global__ __launch_bounds__(256) void gat_attn_b_k(
    const __bf16* __restrict__ XL, const __bf16* __restrict__ XR,
    const float* __restrict__ att, const float* __restrict__ RES,
    __bf16* __restrict__ OUT)
{
  const int wid = blockIdx.x * 4 + (threadIdx.x >> 6);
  const int lane = threadIdx.x & 63;
  const int bl = wid / 900, d = wid - bl * 900;
  constexpr int C2 = FO / 128;
  const size_t base = (size_t)bl * 900 * FO;
  float xrl[C2], xrh[C2], atl[C2], ath[C2];
#pragma unroll
  for (int c = 0; c < C2; ++c) {
    bf16x2 x2 = *(const bf16x2*)(XR + base + (size_t)d * FO + c * 128 + 2 * lane);
    xrl[c] = (float)x2[0]; xrh[c] = (float)x2[1];
    float2 a2 = *(const float2*)(att + c * 128 + 2 * lane);
    atl[c] = a2.x; ath[c] = a2.y;
  }
  float e[30];
#pragma unroll
  for (int j = 0; j < 30; ++j) {
    int s = d + j - 14; if (s < 0) s += 900; if (s >= 900) s -= 900;
    const __bf16* xp = XL + base + (size_t)s * FO;
    float p = 0.f;
#pragma unroll
    for (int c = 0; c < C2; ++c) {
      bf16x2 x2 = *(const bf16x2*)(xp + c * 128 + 2 * lane);
      float vl = (float)x2[0] + xrl[c];
      float vh = (float)x2[1] + xrh[c];
      vl = vl > 0.f ? vl : 0.2f * vl;
      vh = vh > 0.f ? vh : 0.2f * vh;
      p = fmaf(vl, atl[c], p);
      p = fmaf(vh, ath[c], p);
    }
#pragma unroll
    for (int off = 32; off >= 1; off >>= 1) p += __shfl_xor(p, off, 64);
    e[j] = p;
  }
  float m = e[0];
#pragma unroll
  for (int j = 1; j < 30; ++j) m = fmaxf(m, e[j]);
  float sum = 0.f;
#pragma unroll
  for (int j = 0; j < 30; ++j) { e[j] = __expf(e[j] - m); sum += e[j]; }
  float inv = 1.f / sum;
  float accl[C2] = {}, acch[C2] = {};
#pragma unroll
  for (int j = 0; j < 30; ++j) {
    int s = d + j - 14; if (s < 0) s += 900; if (s >= 900) s -= 900;
    const __bf16* xp = XL + base + (size_t)s * FO;
    float al = e[j] * inv;
#pragma unroll
    for (int c = 0; c < C2; ++c) {
      bf16x2 x2 = *(const bf16x2*)(xp + c * 128 + 2 * lane);
      accl[c] = fmaf(al, (float)x2[0], accl[c]);
      acch[c] = fmaf(al, (float)x2[1], acch[c]);
    }
  }
#pragma unroll
  for (int c = 0; c < C2; ++c) {
    size_t idx = base + (size_t)d * FO + c * 128 + 2 * lane;
    float2 r2 = *(const float2*)(RES + idx);
    bf16x2 o2;
    o2[0] = (__bf16)(accl[c] + r2.x);
    o2[1] = (__bf16)(acch[c] + r2.y);
    *(bf16x2*)(OUT + idx) = o2;
  }
}

// ---------------- L2-normalize rows of 1024, f32 in-place + bf16 copy -------
__global__ __launch_bounds__(256) void norm1024b_k(
    float* __restrict__ x, __bf16* __restrict__ xb)
{
  float* p = x + (size_t)blockIdx.x * 1024;
  __bf16* pb = xb + (size_t)blockIdx.x * 1024;
  int t = threadIdx.x;
  float4 v = reinterpret_cast<float4*>(p)[t];
  float ss = v.x * v.x + v.y * v.y + v.z * v.z + v.w * v.w;
#pragma unroll
  for (int off = 32; off >= 1; off >>= 1) ss += __shfl_xor(ss, off, 64);
  __shared__ float w4[4];
  if ((t & 63) == 0) w4[t >> 6] = ss;
  __syncthreads();
  float tot = w4[0] + w4[1] + w4[2] + w4[3];
  float sc = 1.f / fmaxf(sqrtf(tot), 1e-12f);
  v.x *= sc; v.y *= sc; v.z *= sc; v.w *= sc;
  reinterpret_cast<float4*>(p)[t] = v;
  bf16x4 b4;
  b4[0] = (__bf16)v.x; b4[1] = (__bf16)v.y;
  b4[2] = (__bf16)v.z; b4[3] = (__bf16)v.w;
  *(bf16x4*)(pb + t * 4) = b4;
}

// ---------------- softmax rows of 64 (wave/row) -----------------------------
__global__ __launch_bounds__(256) void softmax64_k(float* __restrict__ x)
{
  int r = blockIdx.x * 4 + (threadIdx.x >> 6);
  int lane = threadIdx.x & 63;
  float v = x[(size_t)r * 64 + lane];
  float m = v;
#pragma unroll
  for (int off = 32; off >= 1; off >>= 1) m = fmaxf(m, __shfl_xor(m, off, 64));
  v = __expf(v - m);
  float s = v;
#pragma unroll
  for (int off = 32; off >= 1; off >>= 1) s += __shfl_xor(s, off, 64);
  x[(size_t)r * 64 + lane] = v / s;
}

// ---------------- asum[s,k] = sum_n actc[s,n,k] -----------------------------
__global__ __launch_bounds__(256) void colsum_chunk_k(
    const float* __restrict__ actc, float* __restrict__ asumBase)
{
  int s = blockIdx.x;
  int lane = threadIdx.x & 63, wv = threadIdx.x >> 6;
  const float* ab = actc + (size_t)s * 900 * 64;
  float sum = 0.f;
  for (int n = wv; n < 900; n += 4) sum += ab[(size_t)n * 64 + lane];
  __shared__ float tmp[4][64];
  tmp[wv][lane] = sum;
  __syncthreads();
  if (wv == 0)
    asumBase[s * 64 + lane] = tmp[0][lane] + tmp[1][lane] + tmp[2][lane] + tmp[3][lane];
}

// ---------------- vlad[s,f,k] = sum_n act*feats - asum*cw2 ------------------
__global__ __launch_bounds__(256) void vlad_chunk_k(
    const float* __restrict__ featsc, const float* __restrict__ actc,
    const float* __restrict__ asumBase, const float* __restrict__ cw2,
    float* __restrict__ vladBase)
{
  int s = blockIdx.y, f0 = blockIdx.x * 64;
  int tx = threadIdx.x % 16, ty = threadIdx.x / 16;
  __shared__ float Fs[16][68];
  __shared__ float Ks[16][68];
  float acc[4][4] = {};
  const float* fb = featsc + (size_t)s * 900 * 1024;
  const float* ab = actc + (size_t)s * 900 * 64;
  int nr = threadIdx.x / 16, cq = (threadIdx.x % 16) * 4;
  for (int n0 = 0; n0 < 900; n0 += 16) {
    int n = n0 + nr;
    float4 fv = make_float4(0.f, 0.f, 0.f, 0.f);
    float4 av = make_float4(0.f, 0.f, 0.f, 0.f);
    if (n < 900) {
      fv = *reinterpret_cast<const float4*>(&fb[(size_t)n * 1024 + f0 + cq]);
      av = *reinterpret_cast<const float4*>(&ab[(size_t)n * 64 + cq]);
    }
    *reinterpret_cast<float4*>(&Fs[nr][cq]) = fv;
    *reinterpret_cast<float4*>(&Ks[nr][cq]) = av;
    __syncthreads();
#pragma unroll
    for (int kk = 0; kk < 16; ++kk) {
      float a[4], c[4];
      *reinterpret_cast<float4*>(a) =
          *reinterpret_cast<const float4*>(&Fs[kk][ty * 4]);
      *reinterpret_cast<float4*>(c) =
          *reinterpret_cast<const float4*>(&Ks[kk][tx * 4]);
#pragma unroll
      for (int i = 0; i < 4; ++i)
#pragma unroll
        for (int j = 0; j < 4; ++j)
          acc[i][j] = fmaf(a[i], c[j], acc[i][j]);
    }
    __syncthreads();
  }
#pragma unroll
  for (int i = 0; i < 4; ++i) {
    int f = f0 + ty * 4 + i;
#pragma unroll
    for (int j = 0; j < 4; ++j) {
      int k = tx * 4 + j;
      vladBase[((size_t)s * 1024 + f) * 64 + k] =
          acc[i][j] - asumBase[s * 64 + k] * cw2[f * 64 + k];
    }
  }
}

// ---------------- intra-normalize vlad; emit global scale -------------------
__global__ __launch_bounds__(256) void vlad_norm_k(
    float* __restrict__ vlad, float* __restrict__ gscale)
{
  int b = blockIdx.x;
  int lane = threadIdx.x & 63, wv = threadIdx.x >> 6;
  float* vb = vlad + (size_t)b * 1024 * 64;
  float ss = 0.f;
  for (int f = wv; f < 1024; f += 4) {
    float v = vb[(size_t)f * 64 + lane];
    ss = fmaf(v, v, ss);
  }
  __shared__ float tmp[4][64];
  tmp[wv][lane] = ss;
  __syncthreads();
  float tot = tmp[0][lane] + tmp[1][lane] + tmp[2][lane] + tmp[3][lane];
  float nrm = sqrtf(tot);
  float sc = 1.f / fmaxf(nrm, 1e-12f);
  if (wv == 0) {
    float c = nrm * sc;
    c = c * c;
#pragma unroll
    for (int off = 32; off >= 1; off >>= 1) c += __shfl_xor(c, off, 64);
    if (lane == 0) gscale[b] = 1.f / fmaxf(sqrtf(c), 1e-12f);
  }
  for (int f = wv; f < 1024; f += 4)
    vb[(size_t)f * 64 + lane] *= sc;
}

// ---------------- hidden split-K: 1024 chunks of 64 -------------------------
__global__ __launch_bounds__(256) void hidden_partial2_k(
    const float* __restrict__ vlad, const float* __restrict__ hw,
    float* __restrict__ part)
{
  const int chunk = blockIdx.x;        // 0..1023
  const int k0 = chunk * 64;
  const int o = threadIdx.x;
  __shared__ float vs[32 * 64];
  for (int i = threadIdx.x; i < 2048; i += 256)
    vs[i] = vlad[(size_t)(i >> 6) * 65536 + k0 + (i & 63)];
  __syncthreads();
  float acc[32] = {};
  for (int kk = 0; kk < 64; ++kk) {
    float h = hw[(size_t)(k0 + kk) * 256 + o];
#pragma unroll
    for (int b = 0; b < 32; ++b)
      acc[b] = fmaf(vs[b * 64 + kk], h, acc[b]);
  }
#pragma unroll
  for (int b = 0; b < 32; ++b)
    part[((size_t)chunk * 32 + b) * 256 + o] = acc[b];
}

__global__ __launch_bounds__(1024) void hidden_reduce_k(
    const float* __restrict__ part, const float* __restrict__ gscale,
    float* __restrict__ hidden)
{
  int b = blockIdx.x;
  int o = threadIdx.x & 255, q = threadIdx.x >> 8;
  float s = 0.f;
  for (int c = q; c < 1024; c += 4)
    s += part[((size_t)c * 32 + b) * 256 + o];
  __shared__ float t[4][256];
  t[q][o] = s;
  __syncthreads();
  if (q == 0)
    hidden[b * 256 + o] = (t[0][o] + t[1][o] + t[2][o] + t[3][o]) * gscale[b];
}

// ---------------- BN + gating + final L2 norm -> f32 ------------------------
__global__ __launch_bounds__(256) void final_head_k(
    const float* __restrict__ hidden, const float* __restrict__ bn_g,
    const float* __restrict__ bn_b, const float* __restrict__ gw,
    const float* __restrict__ gb, float* __restrict__ out)
{
  int b = blockIdx.x, o = threadIdx.x;
  __shared__ float vs[256];
  const float inv_bn = 0.99999500003749968f;  // 1/sqrt(1+1e-5)
  float v = hidden[b * 256 + o] * inv_bn * bn_g[o] + bn_b[o];
  vs[o] = v;
  __syncthreads();
  float g = 0.f;
  for (int i = 0; i < 256; ++i) g = fmaf(vs[i], gw[i * 256 + o], g);
  g += gb[o];
  float sig = 1.f / (1.f + __expf(-g));
  float u = v * sig;
  float ss = u * u;
#pragma unroll
  for (int off = 32; off >= 1; off >>= 1) ss += __shfl_xor(ss, off, 64);
  __shared__ float t4[4];
  if ((o & 63) == 0) t4[o >> 6] = ss;
  __syncthreads();
  float tot = t4[0] + t4[1] + t4[2] + t4[3];
  float sc = 1.f / fmaxf(sqrtf(tot), 1e-12f);
  out[b * 256 + o] = u * sc;
}

__global__ __launch_bounds__(256) void zero_out_k(float* out, int n)
{
  int i = blockIdx.x * 256 + threadIdx.x;
  if (i < n) out[i] = 0.f;
}

// ============================================================================
extern "C" void kernel_launch(void* const* d_in, const int* in_sizes, int n_in,
                              void* d_out, int out_size, void* d_ws, size_t ws_size,
                              hipStream_t stream) {
  const float* x_l = (const float*)d_in[0];
  const float* wc[11];
  for (int i = 0; i < 11; ++i) wc[i] = (const float*)d_in[1 + i];
  const float* w_last1 = (const float*)d_in[12];
  const float* w_last2 = (const float*)d_in[13];
  const float* g_wl[3]   = {(const float*)d_in[14], (const float*)d_in[21], (const float*)d_in[28]};
  const float* g_bl[3]   = {(const float*)d_in[15], (const float*)d_in[22], (const float*)d_in[29]};
  const float* g_wr[3]   = {(const float*)d_in[16], (const float*)d_in[23], (const float*)d_in[30]};
  const float* g_br[3]   = {(const float*)d_in[17], (const float*)d_in[24], (const float*)d_in[31]};
  const float* g_att[3]  = {(const float*)d_in[18], (const float*)d_in[25], (const float*)d_in[32]};
  const float* g_res[3]  = {(const float*)d_in[19], (const float*)d_in[26], (const float*)d_in[33]};
  const float* g_bias[3] = {(const float*)d_in[20], (const float*)d_in[27], (const float*)d_in[34]};
  const float* nv_cw   = (const float*)d_in[35];
  const float* nv_cb   = (const float*)d_in[36];
  const float* nv_cw2  = (const float*)d_in[37];
  const float* nv_hw   = (const float*)d_in[38];
  const float* nv_bn_g = (const float*)d_in[39];
  const float* nv_bn_b = (const float*)d_in[40];
  const float* nv_gw   = (const float*)d_in[41];
  const float* nv_gb   = (const float*)d_in[42];
  float* out = (float*)d_out;

  constexpr size_t ARENA_B = 147456000;
  if (ws_size < ARENA_B) {
    zero_out_k<<<dim3((out_size + 255) / 256), dim3(256), 0, stream>>>(out, out_size);
    return;
  }
  char* w8 = (char*)d_ws;
  dim3 blk(256);

  // ---- byte offsets ----
  constexpr size_t OFF_CB0 = 0,          OFF_CB1 = 8000000,   OFF_NODES = 16000000;
  constexpr size_t OFF_XL1 = 31000000,   OFF_XR1 = 46000000,  OFF_RES1 = 61000000;
  constexpr size_t OFF_H1B = 0;
  constexpr size_t OFF_XL23 = 15000000,  OFF_XR23 = 23000000, OFF_RES23 = 31000000;
  constexpr size_t OFF_H2B = 46000000,   OFF_H3B = 76000000;
  constexpr size_t OFF_FEAT = 106000000, OFF_FEATB = 0,       OFF_ACT = 15000000;
  constexpr size_t OFF_VLAD = 17000000,  OFF_ASUM = 25500000, OFF_GSC = 25600000;
  constexpr size_t OFF_HID = 25700000,   OFF_PART = 26000000, OFF_W = 143000000;

  // ---- weight prep (bf16 casts / transposed casts) ----
  __bf16* WB = (__bf16*)(w8 + OFF_W);
  size_t wo = 0;
  auto CAST = [&](const float* s, size_t n) {
    __bf16* d = WB + wo; wo += n;
    cast_bf16_k<<<dim3((unsigned)((n + 255) / 256)), blk, 0, stream>>>(s, d, (int)n);
    return d;
  };
  auto TCAST = [&](const float* s, int Kd, int Nd) {
    __bf16* d = WB + wo; wo += (size_t)Kd * Nd;
    transpose_cast_k<<<dim3((Kd * Nd + 255) / 256), blk, 0, stream>>>(s, d, Kd, Nd);
    return d;
  };
  __bf16* cwb[6];
  for (int i = 0; i < 6; ++i) cwb[i] = CAST(wc[5 + i], 16384);
  __bf16* wl1b = CAST(w_last1, 32768);
  __bf16 *wlT[3], *wrT[3], *resT[3];
  const int FiL[3] = {256, 256, 512}, FoL[3] = {256, 512, 512};
  for (int l = 0; l < 3; ++l) {
    wlT[l]  = TCAST(g_wl[l],  FiL[l], FoL[l]);
    wrT[l]  = TCAST(g_wr[l],  FiL[l], FoL[l]);
    resT[l] = TCAST(g_res[l], FiL[l], FoL[l]);
  }
  __bf16* wl2b = CAST(w_last2, 524288);
  __bf16* cwT = TCAST(nv_cw, 1024, 64);

  // ---- phase 1: tower + 6 conv GEMMs + w_last1 ----
  __bf16* CB0 = (__bf16*)(w8 + OFF_CB0);
  __bf16* CB1 = (__bf16*)(w8 + OFF_CB1);
  __bf16* NODES = (__bf16*)(w8 + OFF_NODES);
  tower_k<<<dim3(3600), blk, 0, stream>>>(x_l, wc[0], wc[1], wc[2], wc[3], wc[4], CB0);
  __bf16* ping = CB0; __bf16* pong = CB1;
  for (int i = 0; i < 6; ++i) {
    gemm_mfma_k<1><<<dim3(1, 225), blk, 0, stream>>>(ping, cwb[i], nullptr, pong,
                                                     28800, 128, 128, 1);
    __bf16* t = ping; ping = pong; pong = t;
  }
  gemm_mfma_k<1><<<dim3(2, 225), blk, 0, stream>>>(ping, wl1b, nullptr, NODES,
                                                   28800, 256, 128, 1);

  // ---- phase 2: GAT layer 1 (full M) ----
  __bf16* XL1 = (__bf16*)(w8 + OFF_XL1);
  __bf16* XR1 = (__bf16*)(w8 + OFF_XR1);
  float* RES1 = (float*)(w8 + OFF_RES1);
  __bf16* H1B = (__bf16*)(w8 + OFF_H1B);
  gemm_mfma_k<1><<<dim3(2, 225), blk, 0, stream>>>(NODES, wlT[0], g_bl[0], XL1, 28800, 256, 256, 0);
  gemm_mfma_k<1><<<dim3(2, 225), blk, 0, stream>>>(NODES, wrT[0], g_br[0], XR1, 28800, 256, 256, 0);
  gemm_mfma_k<0><<<dim3(2, 225), blk, 0, stream>>>(NODES, resT[0], g_bias[0], RES1, 28800, 256, 256, 0);
  gat_attn_b_k<256><<<dim3(7200), blk, 0, stream>>>(XL1, XR1, g_att[0], RES1, H1B);

  // ---- phase 3: GAT layer 2 (4 chunks of 8 samples) ----
  __bf16* XL23 = (__bf16*)(w8 + OFF_XL23);
  __bf16* XR23 = (__bf16*)(w8 + OFF_XR23);
  float* RES23 = (float*)(w8 + OFF_RES23);
  __bf16* H2B = (__bf16*)(w8 + OFF_H2B);
  for (int c = 0; c < 4; ++c) {
    const __bf16* Ax = H1B + (size_t)c * 7200 * 256;
    gemm_mfma_k<1><<<dim3(4, 57), blk, 0, stream>>>(Ax, wlT[1], g_bl[1], XL23, 7200, 512, 256, 0);
    gemm_mfma_k<1><<<dim3(4, 57), blk, 0, stream>>>(Ax, wrT[1], g_br[1], XR23, 7200, 512, 256, 0);
    gemm_mfma_k<0><<<dim3(4, 57), blk, 0, stream>>>(Ax, resT[1], g_bias[1], RES23, 7200, 512, 256, 0);
    gat_attn_b_k<512><<<dim3(1800), blk, 0, stream>>>(XL23, XR23, g_att[1], RES23,
                                                      H2B + (size_t)c * 7200 * 512);
  }
  // ---- phase 4: GAT layer 3 ----
  __bf16* H3B = (__bf16*)(w8 + OFF_H3B);
  for (int c = 0; c < 4; ++c) {
    const __bf16* Ax = H2B + (size_t)c * 7200 * 512;
    gemm_mfma_k<1><<<dim3(4, 57), blk, 0, stream>>>(Ax, wlT[2], g_bl[2], XL23, 7200, 512, 512, 0);
    gemm_mfma_k<1><<<dim3(4, 57), blk, 0, stream>>>(Ax, wrT[2], g_br[2], XR23, 7200, 512, 512, 0);
    gemm_mfma_k<0><<<dim3(4, 57), blk, 0, stream>>>(Ax, resT[2], g_bias[2], RES23, 7200, 512, 512, 0);
    gat_attn_b_k<512><<<dim3(1800), blk, 0, stream>>>(XL23, XR23, g_att[2], RES23,
                                                      H3B + (size_t)c * 7200 * 512);
  }

  // ---- phase 5: feats -> act -> vlad (4 chunks) ----
  float* FEAT = (float*)(w8 + OFF_FEAT);
  __bf16* FEATB = (__bf16*)(w8 + OFF_FEATB);
  float* ACT = (float*)(w8 + OFF_ACT);
  float* VLAD = (float*)(w8 + OFF_VLAD);
  float* ASUM = (float*)(w8 + OFF_ASUM);
  float* GSC = (float*)(w8 + OFF_GSC);
  float* HID = (float*)(w8 + OFF_HID);
  float* PART = (float*)(w8 + OFF_PART);
  for (int c = 0; c < 4; ++c) {
    const __bf16* Ax = H3B + (size_t)c * 7200 * 512;
    gemm_mfma_k<0><<<dim3(8, 57), blk, 0, stream>>>(Ax, wl2b, nullptr, FEAT, 7200, 1024, 512, 1);
    norm1024b_k<<<dim3(7200), blk, 0, stream>>>(FEAT, FEATB);
    gemm_mfma_k<0><<<dim3(1, 57), blk, 0, stream>>>(FEATB, cwT, nv_cb, ACT, 7200, 64, 1024, 0);
    softmax64_k<<<dim3(1800), blk, 0, stream>>>(ACT);
    colsum_chunk_k<<<dim3(8), blk, 0, stream>>>(ACT, ASUM + c * 8 * 64);
    vlad_chunk_k<<<dim3(16, 8), blk, 0, stream>>>(FEAT, ACT, ASUM + c * 8 * 64, nv_cw2,
                                                  VLAD + (size_t)c * 8 * 65536);
  }
  // ---- phase 6 ----
  vlad_norm_k<<<dim3(32), blk, 0, stream>>>(VLAD, GSC);
  hidden_partial2_k<<<dim3(1024), blk, 0, stream>>>(VLAD, nv_hw, PART);
  hidden_reduce_k<<<dim3(32), dim3(1024), 0, stream>>>(PART, GSC, HID);
  final_head_k<<<dim3(32), blk, 0, stream>>>(HID, nv_bn_g, nv_bn_b, nv_gw, nv_gb, out);
  (void)in_sizes; (void)n_in; (void)ws_size;
}

// Round 8
// 2520.124 us; speedup vs baseline: 2.6011x; 1.2504x over previous
//
#include <hip/hip_runtime.h>
#include <hip/hip_bf16.h>
#include <cstdint>

// ============================================================================
// OverlapGATv2 forward. bf16-MFMA GEMMs, wave-per-column conv tower,
// full-M GAT layers (RES bf16), NetVLAD tail.
// Arena (bytes): A@0 (29.49M) | B@29.49M | C1(RES)@58.98M | C2(H)@88.47M |
//   D(NODES/VLAD)@117.96M (14.75M) | E(weights bf16)@132.71M (4.27M) |
//   small@137M.  Peak 137.5 MB (147.456 MB proven available round 4/5).
// ============================================================================

typedef __bf16 bf16x8 __attribute__((ext_vector_type(8)));
typedef __bf16 bf16x4 __attribute__((ext_vector_type(4)));
typedef __bf16 bf16x2 __attribute__((ext_vector_type(2)));
typedef float f32x4 __attribute__((ext_vector_type(4)));

// ---------------- batched weight prep ---------------------------------------
struct CastSeg { const float* s; __bf16* d; int n; int pad; };
struct CastArgs { CastSeg seg[8]; };
__global__ __launch_bounds__(256) void cast_multi_k(CastArgs a)
{
  const CastSeg sg = a.seg[blockIdx.x];
  int i = blockIdx.y * 256 + threadIdx.x;
  if (i < sg.n) sg.d[i] = (__bf16)sg.s[i];
}

// s viewed [K][N] -> d[N][K]
struct TSeg { const float* s; __bf16* d; int K; int N; };
struct TArgs { TSeg seg[16]; };
__global__ __launch_bounds__(256) void tcast_multi_k(TArgs a)
{
  const TSeg sg = a.seg[blockIdx.x];
  int i = blockIdx.y * 256 + threadIdx.x;
  if (i < sg.K * sg.N) {
    int k = i / sg.N, n = i - k * sg.N;
    sg.d[(size_t)n * sg.K + k] = (__bf16)sg.s[i];
  }
}

// ---------------- conv tower v2: wave-per-column, co-major lanes ------------
// weights pre-transposed bf16: wXT[(ci*kh+k)][co]. Activations: per-wave LDS,
// all reads wave-uniform broadcasts (conflict-free).
__global__ __launch_bounds__(256) void tower2_k(
    const float* __restrict__ in,
    const __bf16* __restrict__ w1T,   // [25][16]
    const __bf16* __restrict__ w2T,   // [48][32]
    const __bf16* __restrict__ w3T,   // [96][64]
    const __bf16* __restrict__ w4T,   // [192][64]
    const __bf16* __restrict__ w5T,   // [128][128]
    __bf16* __restrict__ outA)        // [28800][128]
{
  __shared__ float bufA[4][376];
  __shared__ float bufB[4][376];
  const int wv = threadIdx.x >> 6;
  const int lane = threadIdx.x & 63;
  const int colg = blockIdx.x * 4 + wv;
  const int b = colg / 900, w = colg - b * 900;
  float* BA = bufA[wv];
  float* BB = bufB[wv];
  // input ch0..4, rows 0..26 -> BA[ci*27+h]; zero-pad to 144
  for (int idx = lane; idx < 144; idx += 64) {
    float v = 0.f;
    if (idx < 135) {
      int ci = idx / 27, h = idx - ci * 27;
      v = in[((size_t)(b * 5 + ci) * 64 + h) * 900 + w];
    }
    BA[idx] = v;
  }
  __syncthreads();
  { // stage1: Ci=5 kh=5 s1, Co=16 Ho=23. lane=(co,h4): co=lane&15
    const int co = lane & 15, h4 = lane >> 4;
    const int hob = h4 * 6, nho = (h4 == 3) ? 5 : 6;
    float acc[6] = {};
    for (int ci = 0; ci < 5; ++ci)
#pragma unroll
      for (int k = 0; k < 5; ++k) {
        float wt = (float)w1T[(ci * 5 + k) * 16 + co];
#pragma unroll
        for (int i = 0; i < 6; ++i)
          acc[i] = fmaf(BA[ci * 27 + hob + i + k], wt, acc[i]);
      }
    for (int i = 0; i < nho; ++i)
      BB[co * 23 + hob + i] = fmaxf(acc[i], 0.f);
  }
  __syncthreads();
  { // stage2: Ci=16 kh=3 s2, Co=32 Ho=11. lane=(co,h2)
    const int co = lane & 31, h2 = lane >> 5;
    const int hob = h2 * 6, nho = h2 ? 5 : 6;
    float acc[6] = {};
    for (int ci = 0; ci < 16; ++ci)
#pragma unroll
      for (int k = 0; k < 3; ++k) {
        float wt = (float)w2T[(ci * 3 + k) * 32 + co];
#pragma unroll
        for (int i = 0; i < 6; ++i)
          acc[i] = fmaf(BB[ci * 23 + 2 * (hob + i) + k], wt, acc[i]);
      }
    for (int i = 0; i < nho; ++i)
      BA[co * 11 + hob + i] = fmaxf(acc[i], 0.f);
  }
  __syncthreads();
  { // stage3: Ci=32 kh=3 s2, Co=64 Ho=5. lane=co
    float acc[5] = {};
    for (int ci = 0; ci < 32; ++ci)
#pragma unroll
      for (int k = 0; k < 3; ++k) {
        float wt = (float)w3T[(ci * 3 + k) * 64 + lane];
#pragma unroll
        for (int i = 0; i < 5; ++i)
          acc[i] = fmaf(BA[ci * 11 + 2 * i + k], wt, acc[i]);
      }
#pragma unroll
    for (int i = 0; i < 5; ++i)
      BB[lane * 5 + i] = fmaxf(acc[i], 0.f);
  }
  __syncthreads();
  { // stage4: Ci=64 kh=3 s2, Co=64 Ho=2. lane=co
    float a0 = 0.f, a1 = 0.f;
    for (int ci = 0; ci < 64; ++ci)
#pragma unroll
      for (int k = 0; k < 3; ++k) {
        float wt = (float)w4T[(ci * 3 + k) * 64 + lane];
        a0 = fmaf(BB[ci * 5 + k], wt, a0);
        a1 = fmaf(BB[ci * 5 + 2 + k], wt, a1);
      }
    BA[lane * 2 + 0] = fmaxf(a0, 0.f);
    BA[lane * 2 + 1] = fmaxf(a1, 0.f);
  }
  __syncthreads();
  { // stage5: Ci=64 kh=2 s2, Co=128 Ho=1. lane covers co, co+64
    float a0 = 0.f, a1 = 0.f;
    for (int q = 0; q < 128; ++q) {
      float a = BA[q];
      a0 = fmaf(a, (float)w5T[q * 128 + lane], a0);
      a1 = fmaf(a, (float)w5T[q * 128 + 64 + lane], a1);
    }
    __bf16* op = outA + (size_t)colg * 128;
    op[lane] = (__bf16)fmaxf(a0, 0.f);
    op[64 + lane] = (__bf16)fmaxf(a1, 0.f);
  }
}

// ---------------- bf16 MFMA GEMM: C[M,N] = act(A[M,K] @ Bt[N,K]^T + bias) ---
template <int OUTBF16>
__global__ __launch_bounds__(256) void gemm_mfma_k(
    const __bf16* __restrict__ A, const __bf16* __restrict__ Bt,
    const float* __restrict__ bias, void* __restrict__ Cout,
    int M, int N, int K, int relu)
{
  constexpr int LDT = 40;
  __shared__ __bf16 As[128 * LDT];
  __shared__ __bf16 Bs[128 * LDT];
  const int tid = threadIdx.x;
  const int lane = tid & 63, wave = tid >> 6;
  const int wr = wave >> 1, wc = wave & 1;
  const int m0 = blockIdx.y * 128, n0 = blockIdx.x * 128;
  const int l16 = lane & 15, lk = lane >> 4;
  const int sr = tid >> 2;
  const int sc = (tid & 3) * 8;
  f32x4 acc[4][4] = {};
  for (int k0 = 0; k0 < K; k0 += 32) {
#pragma unroll
    for (int p = 0; p < 2; ++p) {
      int r = sr + p * 64;
      bf16x8 va = {};
      if (m0 + r < M)
        va = *(const bf16x8*)(A + (size_t)(m0 + r) * K + k0 + sc);
      *(bf16x8*)(As + r * LDT + sc) = va;
      bf16x8 vb = {};
      if (n0 + r < N)
        vb = *(const bf16x8*)(Bt + (size_t)(n0 + r) * K + k0 + sc);
      *(bf16x8*)(Bs + r * LDT + sc) = vb;
    }
    __syncthreads();
    bf16x8 af[4], bfr[4];
#pragma unroll
    for (int i = 0; i < 4; ++i) {
      af[i]  = *(const bf16x8*)(As + (wr * 64 + i * 16 + l16) * LDT + lk * 8);
      bfr[i] = *(const bf16x8*)(Bs + (wc * 64 + i * 16 + l16) * LDT + lk * 8);
    }
#pragma unroll
    for (int mi = 0; mi < 4; ++mi)
#pragma unroll
      for (int ni = 0; ni < 4; ++ni)
        acc[mi][ni] = __builtin_amdgcn_mfma_f32_16x16x32_bf16(
            af[mi], bfr[ni], acc[mi][ni], 0, 0, 0);
    __syncthreads();
  }
#pragma unroll
  for (int ni = 0; ni < 4; ++ni) {
    int colc = n0 + wc * 64 + ni * 16 + l16;
    if (colc >= N) continue;
    float bs = bias ? bias[colc] : 0.f;
#pragma unroll
    for (int mi = 0; mi < 4; ++mi) {
#pragma unroll
      for (int j = 0; j < 4; ++j) {
        int row = m0 + wr * 64 + mi * 16 + lk * 4 + j;
        if (row >= M) continue;
        float v = acc[mi][ni][j] + bs;
        if (relu) v = fmaxf(v, 0.f);
        if (OUTBF16)
          ((__bf16*)Cout)[(size_t)row * N + colc] = (__bf16)v;
        else
          ((float*)Cout)[(size_t)row * N + colc] = v;
      }
    }
  }
}

// ---------------- GATv2 attention: bf16 XL/XR/RES in, bf16 out --------------
template <int FO>
__global__ __launch_bounds__(256) void gat_attn_b2_k(
    const __bf16* __restrict__ XL, const __bf16* __restrict__ XR,
    const float* __restrict__ att, const __bf16* __restrict__ RES,
    __bf16* __restrict__ OUT)
{
  const int wid = blockIdx.x * 4 + (threadIdx.x >> 6);
  const int lane = threadIdx.x & 63;
  const int bl = wid / 900, d = wid - bl * 900;
  constexpr int C2 = FO / 128;
  const size_t base = (size_t)bl * 900 * FO;
  float xrl[C2], xrh[C2], atl[C2], ath[C2];
#pragma unroll
  for (int c = 0; c < C2; ++c) {
    bf16x2 x2 = *(const bf16x2*)(XR + base + (size_t)d * FO + c * 128 + 2 * lane);
    xrl[c] = (float)x2[0]; xrh[c] = (float)x2[1];
    float2 a2 = *(const float2*)(att + c * 128 + 2 * lane);
    atl[c] = a2.x; ath[c] = a2.y;
  }
  float e[30];
#pragma unroll
  for (int j = 0; j < 30; ++j) {
    int s = d + j - 14; if (s < 0) s += 900; if (s >= 900) s -= 900;
    const __bf16* xp = XL + base + (size_t)s * FO;
    float p = 0.f;
#pragma unroll
    for (int c = 0; c < C2; ++c) {
      bf16x2 x2 = *(const bf16x2*)(xp + c * 128 + 2 * lane);
      float vl = (float)x2[0] + xrl[c];
      float vh = (float)x2[1] + xrh[c];
      vl = vl > 0.f ? vl : 0.2f * vl;
      vh = vh > 0.f ? vh : 0.2f * vh;
      p = fmaf(vl, atl[c], p);
      p = fmaf(vh, ath[c], p);
    }
#pragma unroll
    for (int off = 32; off >= 1; off >>= 1) p += __shfl_xor(p, off, 64);
    e[j] = p;
  }
  float m = e[0];
#pragma unroll
  for (int j = 1; j < 30; ++j) m = fmaxf(m, e[j]);
  float sum = 0.f;
#pragma unroll
  for (int j = 0; j < 30; ++j) { e[j] = __expf(e[j] - m); sum += e[j]; }
  float inv = 1.f / sum;
  float accl[C2] = {}, acch[C2] = {};
#pragma unroll
  for (int j = 0; j < 30; ++j) {
    int s = d + j - 14; if (s < 0) s += 900; if (s >= 900) s -= 900;
    const __bf16* xp = XL + base + (size_t)s * FO;
    float al = e[j] * inv;
#pragma unroll
    for (int c = 0; c < C2; ++c) {
      bf16x2 x2 = *(const bf16x2*)(xp + c * 128 + 2 * lane);
      accl[c] = fmaf(al, (float)x2[0], accl[c]);
      acch[c] = fmaf(al, (float)x2[1], acch[c]);
    }
  }
#pragma unroll
  for (int c = 0; c < C2; ++c) {
    size_t idx = base + (size_t)d * FO + c * 128 + 2 * lane;
    bf16x2 r2 = *(const bf16x2*)(RES + idx);
    bf16x2 o2;
    o2[0] = (__bf16)(accl[c] + (float)r2[0]);
    o2[1] = (__bf16)(acch[c] + (float)r2[1]);
    *(bf16x2*)(OUT + idx) = o2;
  }
}

// ---------------- L2-normalize rows of 1024, f32 in-place + bf16 copy -------
__global__ __launch_bounds__(256) void norm1024b_k(
    float* __restrict__ x, __bf16* __restrict__ xb)
{
  float* p = x + (size_t)blockIdx.x * 1024;
  __bf16* pb = xb + (size_t)blockIdx.x * 1024;
  int t = threadIdx.x;
  float4 v = reinterpret_cast<float4*>(p)[t];
  float ss = v.x * v.x + v.y * v.y + v.z * v.z + v.w * v.w;
#pragma unroll
  for (int off = 32; off >= 1; off >>= 1) ss += __shfl_xor(ss, off, 64);
  __shared__ float w4[4];
  if ((t & 63) == 0) w4[t >> 6] = ss;
  __syncthreads();
  float tot = w4[0] + w4[1] + w4[2] + w4[3];
  float sc = 1.f / fmaxf(sqrtf(tot), 1e-12f);
  v.x *= sc; v.y *= sc; v.z *= sc; v.w *= sc;
  reinterpret_cast<float4*>(p)[t] = v;
  bf16x4 b4;
  b4[0] = (__bf16)v.x; b4[1] = (__bf16)v.y;
  b4[2] = (__bf16)v.z; b4[3] = (__bf16)v.w;
  *(bf16x4*)(pb + t * 4) = b4;
}

// ---------------- softmax rows of 64 ----------------------------------------
__global__ __launch_bounds__(256) void softmax64_k(float* __restrict__ x)
{
  int r = blockIdx.x * 4 + (threadIdx.x >> 6);
  int lane = threadIdx.x & 63;
  float v = x[(size_t)r * 64 + lane];
  float m = v;
#pragma unroll
  for (int off = 32; off >= 1; off >>= 1) m = fmaxf(m, __shfl_xor(m, off, 64));
  v = __expf(v - m);
  float s = v;
#pragma unroll
  for (int off = 32; off >= 1; off >>= 1) s += __shfl_xor(s, off, 64);
  x[(size_t)r * 64 + lane] = v / s;
}

// ---------------- asum[s,k] = sum_n actc[s,n,k] -----------------------------
__global__ __launch_bounds__(256) void colsum_chunk_k(
    const float* __restrict__ actc, float* __restrict__ asumBase)
{
  int s = blockIdx.x;
  int lane = threadIdx.x & 63, wv = threadIdx.x >> 6;
  const float* ab = actc + (size_t)s * 900 * 64;
  float sum = 0.f;
  for (int n = wv; n < 900; n += 4) sum += ab[(size_t)n * 64 + lane];
  __shared__ float tmp[4][64];
  tmp[wv][lane] = sum;
  __syncthreads();
  if (wv == 0)
    asumBase[s * 64 + lane] = tmp[0][lane] + tmp[1][lane] + tmp[2][lane] + tmp[3][lane];
}

// ---------------- vlad[s,f,k] = sum_n act*feats - asum*cw2 ------------------
__global__ __launch_bounds__(256) void vlad_chunk_k(
    const float* __restrict__ featsc, const float* __restrict__ actc,
    const float* __restrict__ asumBase, const float* __restrict__ cw2,
    float* __restrict__ vladBase)
{
  int s = blockIdx.y, f0 = blockIdx.x * 64;
  int tx = threadIdx.x % 16, ty = threadIdx.x / 16;
  __shared__ float Fs[16][68];
  __shared__ float Ks[16][68];
  float acc[4][4] = {};
  const float* fb = featsc + (size_t)s * 900 * 1024;
  const float* ab = actc + (size_t)s * 900 * 64;
  int nr = threadIdx.x / 16, cq = (threadIdx.x % 16) * 4;
  for (int n0 = 0; n0 < 900; n0 += 16) {
    int n = n0 + nr;
    float4 fv = make_float4(0.f, 0.f, 0.f, 0.f);
    float4 av = make_float4(0.f, 0.f, 0.f, 0.f);
    if (n < 900) {
      fv = *reinterpret_cast<const float4*>(&fb[(size_t)n * 1024 + f0 + cq]);
      av = *reinterpret_cast<const float4*>(&ab[(size_t)n * 64 + cq]);
    }
    *reinterpret_cast<float4*>(&Fs[nr][cq]) = fv;
    *reinterpret_cast<float4*>(&Ks[nr][cq]) = av;
    __syncthreads();
#pragma unroll
    for (int kk = 0; kk < 16; ++kk) {
      float a[4], c[4];
      *reinterpret_cast<float4*>(a) =
          *reinterpret_cast<const float4*>(&Fs[kk][ty * 4]);
      *reinterpret_cast<float4*>(c) =
          *reinterpret_cast<const float4*>(&Ks[kk][tx * 4]);
#pragma unroll
      for (int i = 0; i < 4; ++i)
#pragma unroll
        for (int j = 0; j < 4; ++j)
          acc[i][j] = fmaf(a[i], c[j], acc[i][j]);
    }
    __syncthreads();
  }
#pragma unroll
  for (int i = 0; i < 4; ++i) {
    int f = f0 + ty * 4 + i;
#pragma unroll
    for (int j = 0; j < 4; ++j) {
      int k = tx * 4 + j;
      vladBase[((size_t)s * 1024 + f) * 64 + k] =
          acc[i][j] - asumBase[s * 64 + k] * cw2[f * 64 + k];
    }
  }
}

// ---------------- intra-normalize vlad; emit global scale -------------------
__global__ __launch_bounds__(256) void vlad_norm_k(
    float* __restrict__ vlad, float* __restrict__ gscale)
{
  int b = blockIdx.x;
  int lane = threadIdx.x & 63, wv = threadIdx.x >> 6;
  float* vb = vlad + (size_t)b * 1024 * 64;
  float ss = 0.f;
  for (int f = wv; f < 1024; f += 4) {
    float v = vb[(size_t)f * 64 + lane];
    ss = fmaf(v, v, ss);
  }
  __shared__ float tmp[4][64];
  tmp[wv][lane] = ss;
  __syncthreads();
  float tot = tmp[0][lane] + tmp[1][lane] + tmp[2][lane] + tmp[3][lane];
  float nrm = sqrtf(tot);
  float sc = 1.f / fmaxf(nrm, 1e-12f);
  if (wv == 0) {
    float c = nrm * sc;
    c = c * c;
#pragma unroll
    for (int off = 32; off >= 1; off >>= 1) c += __shfl_xor(c, off, 64);
    if (lane == 0) gscale[b] = 1.f / fmaxf(sqrtf(c), 1e-12f);
  }
  for (int f = wv; f < 1024; f += 4)
    vb[(size_t)f * 64 + lane] *= sc;
}

// ---------------- hidden split-K: 512 chunks of 128 -------------------------
__global__ __launch_bounds__(256) void hidden_partial3_k(
    const float* __restrict__ vlad, const float* __restrict__ hw,
    float* __restrict__ part)
{
  const int chunk = blockIdx.x;        // 0..511
  const int k0 = chunk * 128;
  const int o = threadIdx.x;
  __shared__ float vs[32 * 128];
  for (int i = threadIdx.x; i < 4096; i += 256)
    vs[i] = vlad[(size_t)(i >> 7) * 65536 + k0 + (i & 127)];
  __syncthreads();
  float acc[32] = {};
  for (int kk = 0; kk < 128; ++kk) {
    float h = hw[(size_t)(k0 + kk) * 256 + o];
#pragma unroll
    for (int b = 0; b < 32; ++b)
      acc[b] = fmaf(vs[b * 128 + kk], h, acc[b]);
  }
#pragma unroll
  for (int b = 0; b < 32; ++b)
    part[((size_t)chunk * 32 + b) * 256 + o] = acc[b];
}

__global__ __launch_bounds__(1024) void hidden_reduce_k(
    const float* __restrict__ part, const float* __restrict__ gscale,
    float* __restrict__ hidden)
{
  int b = blockIdx.x;
  int o = threadIdx.x & 255, q = threadIdx.x >> 8;
  float s = 0.f;
  for (int c = q; c < 512; c += 4)
    s += part[((size_t)c * 32 + b) * 256 + o];
  __shared__ float t[4][256];
  t[q][o] = s;
  __syncthreads();
  if (q == 0)
    hidden[b * 256 + o] = (t[0][o] + t[1][o] + t[2][o] + t[3][o]) * gscale[b];
}

// ---------------- BN + gating + final L2 norm -> f32 ------------------------
__global__ __launch_bounds__(256) void final_head_k(
    const float* __restrict__ hidden, const float* __restrict__ bn_g,
    const float* __restrict__ bn_b, const float* __restrict__ gw,
    const float* __restrict__ gb, float* __restrict__ out)
{
  int b = blockIdx.x, o = threadIdx.x;
  __shared__ float vs[256];
  const float inv_bn = 0.99999500003749968f;  // 1/sqrt(1+1e-5)
  float v = hidden[b * 256 + o] * inv_bn * bn_g[o] + bn_b[o];
  vs[o] = v;
  __syncthreads();
  float g = 0.f;
  for (int i = 0; i < 256; ++i) g = fmaf(vs[i], gw[i * 256 + o], g);
  g += gb[o];
  float sig = 1.f / (1.f + __expf(-g));
  float u = v * sig;
  float ss = u * u;
#pragma unroll
  for (int off = 32; off >= 1; off >>= 1) ss += __shfl_xor(ss, off, 64);
  __shared__ float t4[4];
  if ((o & 63) == 0) t4[o >> 6] = ss;
  __syncthreads();
  float tot = t4[0] + t4[1] + t4[2] + t4[3];
  float sc = 1.f / fmaxf(sqrtf(tot), 1e-12f);
  out[b * 256 + o] = u * sc;
}

__global__ __launch_bounds__(256) void zero_out_k(float* out, int n)
{
  int i = blockIdx.x * 256 + threadIdx.x;
  if (i < n) out[i] = 0.f;
}

// ============================================================================
extern "C" void kernel_launch(void* const* d_in, const int* in_sizes, int n_in,
                              void* d_out, int out_size, void* d_ws, size_t ws_size,
                              hipStream_t stream) {
  const float* x_l = (const float*)d_in[0];
  const float* wc[11];
  for (int i = 0; i < 11; ++i) wc[i] = (const float*)d_in[1 + i];
  const float* w_last1 = (const float*)d_in[12];
  const float* w_last2 = (const float*)d_in[13];
  const float* g_wl[3]   = {(const float*)d_in[14], (const float*)d_in[21], (const float*)d_in[28]};
  const float* g_bl[3]   = {(const float*)d_in[15], (const float*)d_in[22], (const float*)d_in[29]};
  const float* g_wr[3]   = {(const float*)d_in[16], (const float*)d_in[23], (const float*)d_in[30]};
  const float* g_br[3]   = {(const float*)d_in[17], (const float*)d_in[24], (const float*)d_in[31]};
  const float* g_att[3]  = {(const float*)d_in[18], (const float*)d_in[25], (const float*)d_in[32]};
  const float* g_res[3]  = {(const float*)d_in[19], (const float*)d_in[26], (const float*)d_in[33]};
  const float* g_bias[3] = {(const float*)d_in[20], (const float*)d_in[27], (const float*)d_in[34]};
  const float* nv_cw   = (const float*)d_in[35];
  const float* nv_cb   = (const float*)d_in[36];
  const float* nv_cw2  = (const float*)d_in[37];
  const float* nv_hw   = (const float*)d_in[38];
  const float* nv_bn_g = (const float*)d_in[39];
  const float* nv_bn_b = (const float*)d_in[40];
  const float* nv_gw   = (const float*)d_in[41];
  const float* nv_gb   = (const float*)d_in[42];
  float* out = (float*)d_out;

  constexpr size_t ARENA_B = 137500000;
  if (ws_size < ARENA_B) {
    zero_out_k<<<dim3((out_size + 255) / 256), dim3(256), 0, stream>>>(out, out_size);
    return;
  }
  char* w8 = (char*)d_ws;
  dim3 blk(256);

  // ---- regions (bytes) ----
  constexpr size_t OFF_A  = 0;
  constexpr size_t OFF_B  = 29491200;
  constexpr size_t OFF_C1 = 58982400;   // RES (bf16)
  constexpr size_t OFF_C2 = 88473600;   // H (bf16)
  constexpr size_t OFF_D  = 117964800;  // NODES / VLAD
  constexpr size_t OFF_E  = 132710400;  // bf16 weights
  constexpr size_t OFF_ASUM = 137000000, OFF_GSC = 137100000, OFF_HID = 137200000;

  // ---- weight prep: bf16 element offsets inside E ----
  __bf16* WB = (__bf16*)(w8 + OFF_E);
  __bf16* cwb[6];
  for (int i = 0; i < 6; ++i) cwb[i] = WB + (size_t)i * 16384;
  __bf16* wl1b = WB + 98304;
  __bf16* wl2b = WB + 131072;
  __bf16* wlT[3]  = {WB + 655360, WB + 851968,  WB + 1245184};
  __bf16* wrT[3]  = {WB + 720896, WB + 983040,  WB + 1507328};
  __bf16* resT[3] = {WB + 786432, WB + 1114112, WB + 1769472};
  __bf16* cwT = WB + 2031616;
  __bf16* w1T = WB + 2097152;
  __bf16* w2T = WB + 2097552;
  __bf16* w3T = WB + 2099088;
  __bf16* w4T = WB + 2105232;
  __bf16* w5T = WB + 2117520;

  {
    CastArgs ca;
    for (int i = 0; i < 6; ++i) ca.seg[i] = {wc[5 + i], cwb[i], 16384, 0};
    ca.seg[6] = {w_last1, wl1b, 32768, 0};
    ca.seg[7] = {w_last2, wl2b, 524288, 0};
    cast_multi_k<<<dim3(8, 2048), blk, 0, stream>>>(ca);
    TArgs ta;
    const int FiL[3] = {256, 256, 512}, FoL[3] = {256, 512, 512};
    for (int l = 0; l < 3; ++l) {
      ta.seg[l * 3 + 0] = {g_wl[l],  wlT[l],  FiL[l], FoL[l]};
      ta.seg[l * 3 + 1] = {g_wr[l],  wrT[l],  FiL[l], FoL[l]};
      ta.seg[l * 3 + 2] = {g_res[l], resT[l], FiL[l], FoL[l]};
    }
    ta.seg[9]  = {nv_cw, cwT, 1024, 64};
    ta.seg[10] = {wc[0], w1T, 16, 25};
    ta.seg[11] = {wc[1], w2T, 32, 48};
    ta.seg[12] = {wc[2], w3T, 64, 96};
    ta.seg[13] = {wc[3], w4T, 64, 192};
    ta.seg[14] = {wc[4], w5T, 128, 128};
    ta.seg[15] = {nullptr, nullptr, 0, 0};
    tcast_multi_k<<<dim3(16, 1024), blk, 0, stream>>>(ta);
  }

  // ---- phase 1: tower + conv-GEMM chain + w_last1 ----
  __bf16* Abuf = (__bf16*)(w8 + OFF_A);
  __bf16* Bbuf = (__bf16*)(w8 + OFF_B);
  __bf16* NODES = (__bf16*)(w8 + OFF_D);
  tower2_k<<<dim3(7200), blk, 0, stream>>>(x_l, w1T, w2T, w3T, w4T, w5T, Abuf);
  __bf16* ping = Abuf; __bf16* pong = Bbuf;
  for (int i = 0; i < 6; ++i) {
    gemm_mfma_k<1><<<dim3(1, 225), blk, 0, stream>>>(ping, cwb[i], nullptr, pong,
                                                     28800, 128, 128, 1);
    __bf16* t = ping; ping = pong; pong = t;
  }
  gemm_mfma_k<1><<<dim3(2, 225), blk, 0, stream>>>(ping, wl1b, nullptr, NODES,
                                                   28800, 256, 128, 1);

  __bf16* RESb = (__bf16*)(w8 + OFF_C1);
  __bf16* Hb   = (__bf16*)(w8 + OFF_C2);

  // ---- phase 2: GAT layer 1 (Fi=256, Fo=256), full M ----
  gemm_mfma_k<1><<<dim3(2, 225), blk, 0, stream>>>(NODES, wlT[0], g_bl[0], Abuf, 28800, 256, 256, 0);
  gemm_mfma_k<1><<<dim3(2, 225), blk, 0, stream>>>(NODES, wrT[0], g_br[0], Bbuf, 28800, 256, 256, 0);
  gemm_mfma_k<1><<<dim3(2, 225), blk, 0, stream>>>(NODES, resT[0], g_bias[0], RESb, 28800, 256, 256, 0);
  gat_attn_b2_k<256><<<dim3(7200), blk, 0, stream>>>(Abuf, Bbuf, g_att[0], RESb, Hb);

  // ---- phase 3: GAT layer 2 (256 -> 512), full M ----
  gemm_mfma_k<1><<<dim3(4, 225), blk, 0, stream>>>(Hb, wlT[1], g_bl[1], Abuf, 28800, 512, 256, 0);
  gemm_mfma_k<1><<<dim3(4, 225), blk, 0, stream>>>(Hb, wrT[1], g_br[1], Bbuf, 28800, 512, 256, 0);
  gemm_mfma_k<1><<<dim3(4, 225), blk, 0, stream>>>(Hb, resT[1], g_bias[1], RESb, 28800, 512, 256, 0);
  gat_attn_b2_k<512><<<dim3(7200), blk, 0, stream>>>(Abuf, Bbuf, g_att[1], RESb, Hb);

  // ---- phase 4: GAT layer 3 (512 -> 512), full M ----
  gemm_mfma_k<1><<<dim3(4, 225), blk, 0, stream>>>(Hb, wlT[2], g_bl[2], Abuf, 28800, 512, 512, 0);
  gemm_mfma_k<1><<<dim3(4, 225), blk, 0, stream>>>(Hb, wrT[2], g_br[2], Bbuf, 28800, 512, 512, 0);
  gemm_mfma_k<1><<<dim3(4, 225), blk, 0, stream>>>(Hb, resT[2], g_bias[2], RESb, 28800, 512, 512, 0);
  gat_attn_b2_k<512><<<dim3(7200), blk, 0, stream>>>(Abuf, Bbuf, g_att[2], RESb, Hb);

  // ---- phase 5: feats -> act -> vlad (4 chunks of 8 samples) ----
  float* FEAT = (float*)(w8 + OFF_A);
  __bf16* FEATB = (__bf16*)(w8 + OFF_B);
  float* ACT = (float*)(w8 + OFF_B + 16000000);
  float* VLAD = (float*)(w8 + OFF_D);
  float* ASUM = (float*)(w8 + OFF_ASUM);
  float* GSC = (float*)(w8 + OFF_GSC);
  float* HID = (float*)(w8 + OFF_HID);
  float* PART = (float*)(w8 + OFF_C1);
  for (int c = 0; c < 4; ++c) {
    const __bf16* Ax = Hb + (size_t)c * 7200 * 512;
    gemm_mfma_k<0><<<dim3(8, 57), blk, 0, stream>>>(Ax, wl2b, nullptr, FEAT, 7200, 1024, 512, 1);
    norm1024b_k<<<dim3(7200), blk, 0, stream>>>(FEAT, FEATB);
    gemm_mfma_k<0><<<dim3(1, 57), blk, 0, stream>>>(FEATB, cwT, nv_cb, ACT, 7200, 64, 1024, 0);
    softmax64_k<<<dim3(1800), blk, 0, stream>>>(ACT);
    colsum_chunk_k<<<dim3(8), blk, 0, stream>>>(ACT, ASUM + c * 8 * 64);
    vlad_chunk_k<<<dim3(16, 8), blk, 0, stream>>>(FEAT, ACT, ASUM + c * 8 * 64, nv_cw2,
                                                  VLAD + (size_t)c * 8 * 65536);
  }
  // ---- phase 6 ----
  vlad_norm_k<<<dim3(32), blk, 0, stream>>>(VLAD, GSC);
  hidden_partial3_k<<<dim3(512), blk, 0, stream>>>(VLAD, nv_hw, PART);
  hidden_reduce_k<<<dim3(32), dim3(1024), 0, stream>>>(PART, GSC, HID);
  final_head_k<<<dim3(32), blk, 0, stream>>>(HID, nv_bn_g, nv_bn_b, nv_gw, nv_gb, out);
  (void)in_sizes; (void)n_in; (void)ws_size;
}